// Round 7
// baseline (592.768 us; speedup 1.0000x reference)
//
#include <hip/hip_runtime.h>

#define BB     256
#define TT     2048
#define DIN    10
#define UU     64
#define DOUT   2
#define CHUNK  64
#define NCHUNK (TT / CHUNK)
#define HISTP  67   // odd stride -> conflict-free column reads

typedef float f32x2 __attribute__((ext_vector_type(2)));
typedef float f32x4 __attribute__((ext_vector_type(4)));

// 2*log2(e): recurrence tracked as u = 1/(exp2(C*z)+1), h = 1-2u = tanh(z)
#define CSCALE 2.8853900817779268f

#if __has_builtin(__builtin_elementwise_fma)
__device__ __forceinline__ f32x2 pkfma(f32x2 a, f32x2 b, f32x2 c) {
    return __builtin_elementwise_fma(a, b, c);
}
#else
__device__ __forceinline__ f32x2 pkfma(f32x2 a, f32x2 b, f32x2 c) {
    f32x2 r; r.x = fmaf(a.x, b.x, c.x); r.y = fmaf(a.y, b.y, c.y); return r;
}
#endif

#if __has_builtin(__builtin_amdgcn_permlane32_swap) && __has_builtin(__builtin_amdgcn_permlane16_swap)
#define HAS_PL 1
#else
#define HAS_PL 0
#endif

template <int N> struct IC { static constexpr int value = N; };

#if HAS_PL
__device__ __forceinline__ float swapadd32(float a, float b) {
    auto t = __builtin_amdgcn_permlane32_swap(__float_as_uint(a), __float_as_uint(b), false, false);
    return __uint_as_float(t[0]) + __uint_as_float(t[1]);
}
__device__ __forceinline__ float pl32_first(float v) {
    auto t = __builtin_amdgcn_permlane32_swap(__float_as_uint(v), __float_as_uint(v), false, false);
    return __uint_as_float(t[0]);
}
__device__ __forceinline__ float swapadd16(float a, float b) {
    auto t = __builtin_amdgcn_permlane16_swap(__float_as_uint(a), __float_as_uint(b), false, false);
    return __uint_as_float(t[0]) + __uint_as_float(t[1]);
}
__device__ __forceinline__ float pl16_first(float v) {
    auto t = __builtin_amdgcn_permlane16_swap(__float_as_uint(v), __float_as_uint(v), false, false);
    return __uint_as_float(t[0]);
}
#endif

__device__ __forceinline__ float swz_xor16(float v) {
    return __int_as_float(__builtin_amdgcn_ds_swizzle(__float_as_int(v), 0x401F));
}

// 15 DPP row-rotations writing directly into packed pk_fma operand pairs:
// hp[J/2].{x,y} = u from lane (l & 0x30) | ((r + J*dstep) & 15)
template <int J>
__device__ __forceinline__ void ror_fill(int hb, f32x2* hp) {
    float v = __int_as_float(__builtin_amdgcn_mov_dpp(hb, 0x120 + J, 0xF, 0xF, false));
    if constexpr ((J & 1) == 0) hp[J / 2].x = v; else hp[J / 2].y = v;
    if constexpr (J < 15) ror_fill<J + 1>(hb, hp);
}

// Reduce-scatter across the 4 k-quarters. MODE 0: all-VALU permlane network.
// MODE 2: shfl + ds_swizzle fallback (proven R3-R6).
template <int MODE>
__device__ __forceinline__ float reduce4(float p0, float p1, float p2, float p3, int l) {
#if HAS_PL
    if constexpr (MODE == 0) {
        float u02 = swapadd32(p0, p2);
        float u13 = swapadd32(p1, p3);
        return swapadd16(u02, u13);
    }
#endif
    {
        bool hi = (l & 32) != 0, od = (l & 16) != 0;
        float s0 = hi ? p0 : p2, s1 = hi ? p1 : p3;
        float r0 = __shfl_xor(s0, 32), r1 = __shfl_xor(s1, 32);
        float a0 = (hi ? p2 : p0) + r0;
        float a1 = (hi ? p3 : p1) + r1;
        float s2 = od ? a0 : a1;
        float r2 = swz_xor16(s2);
        return (od ? a1 : a0) + r2;
    }
}

__global__ __launch_bounds__(128) void rnn_scan_kernel(
    const float* __restrict__ x,    // [B,T,DIN]
    const float* __restrict__ Wx,   // [DIN,U]
    const float* __restrict__ Wh,   // [U,U]
    const float* __restrict__ bias, // [U]
    const float* __restrict__ Wd,   // [U,DOUT]
    const float* __restrict__ bd,   // [DOUT]
    float* __restrict__ out)        // [B,T,DOUT]
{
    // Block owns TWO sequences. Wave 0: dual interleaved scan (two independent
    // dependency chains fill each other's latency bubbles). Wave 1: producer
    // (x-projection c+1, Dense epilogue c-1, for both sequences).
    __shared__ float xps[2][2][CHUNK * UU];     // [seq][buf][s*UU + l]
    __shared__ float hist[2][2][CHUNK * HISTP]; // [seq][buf][s*HISTP + l]
    __shared__ __align__(16) float xs[CHUNK * 12];
    __shared__ __align__(8)  f32x2 wdl2[UU];    // -2*Wd rows

    const int tid = threadIdx.x;
    const int wid = tid >> 6;
    const int l   = tid & 63;
    const int g   = l >> 4;
    const int r   = l & 15;
    const int bA  = 2 * blockIdx.x;

    // --- probe DPP row_ror direction (init-only, direction-proof) ---
    int dstep;
    {
        int q = __builtin_amdgcn_mov_dpp(r, 0x121, 0xF, 0xF, false);
        dstep = (q - r) & 15;
    }

    // --- probe permlane swap semantics; pick reduce mode + relabel bits ---
    int mode = 2, alt32 = 0, alt16 = 0;
#if HAS_PL
    {
        float A = pl32_first((l & 32) ? 2.0f : 1.0f);
        int m0 = __all(A == 1.0f), m1 = __all(A == 2.0f);
        if (m0 | m1) {
            float Bv = pl16_first((float)g);
            int n0 = __all(Bv == (float)(g & ~1)), n1 = __all(Bv == (float)(g | 1));
            if (n0 | n1) { mode = 0; alt32 = m1 ? 1 : 0; alt16 = n1 ? 1 : 0; }
        }
    }
#endif
    if (mode != 0) { alt32 = 0; alt16 = 0; }

    // --- Wh fragments, scaled: W2'[k,c] = -2*C*Wh[k,c] (shared by both seqs) ---
    f32x2 w2[4][8];
#pragma unroll
    for (int j = 0; j < 4; ++j) {
        const int rho = ((j & 1) ^ alt16) | ((((j >> 1) & 1) ^ alt32) << 1);
        const int cj = r + 16 * rho;
#pragma unroll
        for (int m = 0; m < 8; ++m) {
            const int k0 = 16 * g + ((r + (2 * m) * dstep) & 15);
            const int k1 = 16 * g + ((r + (2 * m + 1) * dstep) & 15);
            f32x2 w;
            w.x = -2.0f * CSCALE * Wh[(size_t)k0 * UU + cj];
            w.y = -2.0f * CSCALE * Wh[(size_t)k1 * UU + cj];
            w2[j][m] = w;
        }
    }

    // --- producer constants ---
    f32x2 wxp[5];
#pragma unroll
    for (int d2 = 0; d2 < 5; ++d2) {
        f32x2 w;
        w.x = CSCALE * Wx[(2 * d2) * UU + l];
        w.y = CSCALE * Wx[(2 * d2 + 1) * UU + l];
        wxp[d2] = w;
    }
    float Kl;
    {
        float s = bias[l];
        for (int k = 0; k < UU; ++k) s += Wh[(size_t)k * UU + l];
        Kl = CSCALE * s;
    }
    f32x2 bdd;
    {
        float s0 = bd[0], s1 = bd[1];
        for (int k = 0; k < UU; ++k) { s0 += Wd[k * DOUT + 0]; s1 += Wd[k * DOUT + 1]; }
        bdd.x = s0; bdd.y = s1;
    }

    const float* xbA = x + (size_t)bA * TT * DIN;
    const float* xbB = xbA + (size_t)TT * DIN;
    float*       obA = out + (size_t)bA * TT * DOUT;
    float*       obB = obA + (size_t)TT * DOUT;

    // --- producer helpers (wave 1 only; same-wave DS ordering, no barriers) ---
    auto fill_xps = [&](const float* xbq, float* xpd, int cn) {
        const f32x2* xr = (const f32x2*)(xbq + (size_t)(cn * CHUNK + l) * DIN);
        f32x2 v0 = xr[0], v1 = xr[1], v2 = xr[2], v3 = xr[3], v4 = xr[4];
        f32x2* dst = (f32x2*)&xs[l * 12];
        dst[0] = v0; dst[1] = v1; dst[2] = v2; dst[3] = v3; dst[4] = v4;
#pragma unroll 4
        for (int s = 0; s < CHUNK; ++s) {
            const float* p = &xs[s * 12];
            f32x4 xa = ((const f32x4*)p)[0];
            f32x4 xc = ((const f32x4*)p)[1];
            f32x2 xe = ((const f32x2*)p)[4];
            f32x2 acc = {Kl, 0.0f};
            acc = pkfma(__builtin_shufflevector(xa, xa, 0, 1), wxp[0], acc);
            acc = pkfma(__builtin_shufflevector(xa, xa, 2, 3), wxp[1], acc);
            acc = pkfma(__builtin_shufflevector(xc, xc, 0, 1), wxp[2], acc);
            acc = pkfma(__builtin_shufflevector(xc, xc, 2, 3), wxp[3], acc);
            acc = pkfma(xe, wxp[4], acc);
            xpd[s * UU + l] = acc.x + acc.y;
        }
    };
    auto dense_chunk = [&](const float* hbuf, float* obq, int cd) {
        const float* hrow = hbuf + l * HISTP;
        f32x2 acc = bdd;
#pragma unroll 8
        for (int k = 0; k < UU; ++k) {
            float u = hrow[k];
            f32x2 uu; uu.x = u; uu.y = u;
            acc = pkfma(uu, wdl2[k], acc);
        }
        float2 o; o.x = acc.x; o.y = acc.y;
        *(float2*)(obq + (size_t)(cd * CHUNK + l) * DOUT) = o;
    };

    // prologue
    if (wid == 1) {
        f32x2 w; w.x = -2.0f * Wd[l * DOUT + 0]; w.y = -2.0f * Wd[l * DOUT + 1];
        wdl2[l] = w;
        fill_xps(xbA, &xps[0][0][0], 0);
        fill_xps(xbB, &xps[1][0][0], 0);
    }
    __syncthreads();

    float uA = 0.5f, uB = 0.5f;   // h_0 = 0

    // --- dual interleaved scan of one chunk (two independent chains) ---
    auto scan2 = [&](auto MC, int c) {
        constexpr int MODE = decltype(MC)::value;
        const float* xA = &xps[0][c & 1][l];
        const float* xB = &xps[1][c & 1][l];
        float* hA = &hist[0][c & 1][l];
        float* hB = &hist[1][c & 1][l];
        float pfA[4], pfB[4];
#pragma unroll
        for (int i = 0; i < 4; ++i) { pfA[i] = xA[i * UU]; pfB[i] = xB[i * UU]; }
#pragma unroll 1
        for (int sb = 0; sb < CHUNK; sb += 4) {
            const int sn = (sb + 4 < CHUNK) ? (sb + 4) : 0;  // clamp: branch-free
            float nA[4], nB[4];
#pragma unroll
            for (int i = 0; i < 4; ++i) { nA[i] = xA[(sn + i) * UU]; nB[i] = xB[(sn + i) * UU]; }
#pragma unroll
            for (int j = 0; j < 4; ++j) {
                const int s = sb + j;
                f32x2 hpA[8], hpB[8];
                hpA[0].x = uA; hpB[0].x = uB;
                ror_fill<1>(__float_as_int(uA), hpA);
                ror_fill<1>(__float_as_int(uB), hpB);
                f32x2 aA0 = {0.f,0.f}, aA1 = {0.f,0.f}, aA2 = {0.f,0.f}, aA3 = {0.f,0.f};
                f32x2 aB0 = {0.f,0.f}, aB1 = {0.f,0.f}, aB2 = {0.f,0.f}, aB3 = {0.f,0.f};
#pragma unroll
                for (int m = 0; m < 8; ++m) {
                    aA0 = pkfma(hpA[m], w2[0][m], aA0);
                    aB0 = pkfma(hpB[m], w2[0][m], aB0);
                    aA1 = pkfma(hpA[m], w2[1][m], aA1);
                    aB1 = pkfma(hpB[m], w2[1][m], aB1);
                    aA2 = pkfma(hpA[m], w2[2][m], aA2);
                    aB2 = pkfma(hpB[m], w2[2][m], aB2);
                    aA3 = pkfma(hpA[m], w2[3][m], aA3);
                    aB3 = pkfma(hpB[m], w2[3][m], aB3);
                }
                float zrA = reduce4<MODE>(aA0.x + aA0.y, aA1.x + aA1.y,
                                          aA2.x + aA2.y, aA3.x + aA3.y, l);
                float zrB = reduce4<MODE>(aB0.x + aB0.y, aB1.x + aB1.y,
                                          aB2.x + aB2.y, aB3.x + aB3.y, l);
                float zpA = zrA + pfA[j];
                float zpB = zrB + pfB[j];
#if __has_builtin(__builtin_amdgcn_exp2f)
                float eA = __builtin_amdgcn_exp2f(zpA);
                float eB = __builtin_amdgcn_exp2f(zpB);
#else
                float eA = exp2f(zpA);
                float eB = exp2f(zpB);
#endif
                uA = __builtin_amdgcn_rcpf(eA + 1.0f);
                uB = __builtin_amdgcn_rcpf(eB + 1.0f);
                hA[s * HISTP] = uA;
                hB[s * HISTP] = uB;
            }
#pragma unroll
            for (int i = 0; i < 4; ++i) { pfA[i] = nA[i]; pfB[i] = nB[i]; }
        }
    };

    for (int c = 0; c < NCHUNK; ++c) {
        if (wid == 0) {
            if (mode == 0) scan2(IC<0>{}, c);
            else           scan2(IC<2>{}, c);
        } else {
            if (c + 1 < NCHUNK) {
                fill_xps(xbA, &xps[0][(c + 1) & 1][0], c + 1);
                fill_xps(xbB, &xps[1][(c + 1) & 1][0], c + 1);
            }
            if (c > 0) {
                dense_chunk(&hist[0][(c - 1) & 1][0], obA, c - 1);
                dense_chunk(&hist[1][(c - 1) & 1][0], obB, c - 1);
            }
        }
        __syncthreads();
    }
    if (wid == 1) {
        dense_chunk(&hist[0][(NCHUNK - 1) & 1][0], obA, NCHUNK - 1);
        dense_chunk(&hist[1][(NCHUNK - 1) & 1][0], obB, NCHUNK - 1);
    }
}

extern "C" void kernel_launch(void* const* d_in, const int* in_sizes, int n_in,
                              void* d_out, int out_size, void* d_ws, size_t ws_size,
                              hipStream_t stream) {
    const float* x    = (const float*)d_in[0];
    const float* Wx   = (const float*)d_in[1];
    const float* Wh   = (const float*)d_in[2];
    const float* bias = (const float*)d_in[3];
    const float* Wd   = (const float*)d_in[4];
    const float* bd   = (const float*)d_in[5];
    float* out = (float*)d_out;

    rnn_scan_kernel<<<BB / 2, 128, 0, stream>>>(x, Wx, Wh, bias, Wd, bd, out);
}

// Round 8
// 318.198 us; speedup vs baseline: 1.8629x; 1.8629x over previous
//
#include <hip/hip_runtime.h>

#define BB     256
#define TT     2048
#define DIN    10
#define UU     64
#define DOUT   2
#define CHUNK  64
#define NCHUNK (TT / CHUNK)
#define HISTP  67   // odd stride -> conflict-free column reads

typedef float f32x2 __attribute__((ext_vector_type(2)));
typedef float f32x4 __attribute__((ext_vector_type(4)));

// 2*log2(e): recurrence tracked as u = 1/(exp2(C*z)+1), h = 1-2u = tanh(z)
#define CSCALE 2.8853900817779268f

#if __has_builtin(__builtin_elementwise_fma)
__device__ __forceinline__ f32x2 pkfma(f32x2 a, f32x2 b, f32x2 c) {
    return __builtin_elementwise_fma(a, b, c);
}
#else
__device__ __forceinline__ f32x2 pkfma(f32x2 a, f32x2 b, f32x2 c) {
    f32x2 r; r.x = fmaf(a.x, b.x, c.x); r.y = fmaf(a.y, b.y, c.y); return r;
}
#endif

#if __has_builtin(__builtin_amdgcn_permlane32_swap) && __has_builtin(__builtin_amdgcn_permlane16_swap)
#define HAS_PL 1
#else
#define HAS_PL 0
#endif

template <int N> struct IC { static constexpr int value = N; };

#if HAS_PL
// gfx950 v_permlane32_swap_b32: swaps upper 32 lanes of vdst with lower 32
// lanes of vsrc. swapadd32(a,b)[l] = l<32 ? a[l]+a[l+32] : b[l-32]+b[l].
__device__ __forceinline__ float swapadd32(float a, float b) {
    auto t = __builtin_amdgcn_permlane32_swap(__float_as_uint(a), __float_as_uint(b), false, false);
    return __uint_as_float(t[0]) + __uint_as_float(t[1]);
}
// v_permlane16_swap_b32: swaps odd 16-lane rows of vdst with even rows of vsrc.
// swapadd16(a,b)[l] = (l&16)==0 ? a[l]+a[l^16] : b[l^16]+b[l].
__device__ __forceinline__ float swapadd16(float a, float b) {
    auto t = __builtin_amdgcn_permlane16_swap(__float_as_uint(a), __float_as_uint(b), false, false);
    return __uint_as_float(t[0]) + __uint_as_float(t[1]);
}
#endif

__device__ __forceinline__ float swz_xor16(float v) {
    return __int_as_float(__builtin_amdgcn_ds_swizzle(__float_as_int(v), 0x401F));
}

// 15 DPP row-rotations writing directly into packed pk_fma operand pairs:
// hp[J/2].{x,y} = u from lane (l & 0x30) | ((r + J*dstep) & 15)
template <int J>
__device__ __forceinline__ void ror_fill(int hb, f32x2* hp) {
    float v = __int_as_float(__builtin_amdgcn_mov_dpp(hb, 0x120 + J, 0xF, 0xF, false));
    if constexpr ((J & 1) == 0) hp[J / 2].x = v; else hp[J / 2].y = v;
    if constexpr (J < 15) ror_fill<J + 1>(hb, hp);
}

// Reduce-scatter across the 4 k-quarters; unit l's full 64-k sum lands on
// lane l. Both modes use IDENTICAL slot->column layout (cj = r + 16j).
// MODE 0: 3 VALU permlane-swaps (no DS pipe on the chain).
// MODE 2: shfl_xor + ds_swizzle fallback (proven R3-R7).
template <int MODE>
__device__ __forceinline__ float reduce4(float p0, float p1, float p2, float p3, int l) {
#if HAS_PL
    if constexpr (MODE == 0) {
        float u02 = swapadd32(p0, p2);  // lo: p0 over quarters {g,g+2}; hi: p2
        float u13 = swapadd32(p1, p3);
        return swapadd16(u02, u13);     // row g: slot g's unit, all 64 k
    }
#endif
    {
        bool hi = (l & 32) != 0, od = (l & 16) != 0;
        float s0 = hi ? p0 : p2, s1 = hi ? p1 : p3;
        float r0 = __shfl_xor(s0, 32), r1 = __shfl_xor(s1, 32);
        float a0 = (hi ? p2 : p0) + r0;
        float a1 = (hi ? p3 : p1) + r1;
        float s2 = od ? a0 : a1;
        float r2 = swz_xor16(s2);
        return (od ? a1 : a0) + r2;
    }
}

__global__ __launch_bounds__(128) void rnn_scan_kernel(
    const float* __restrict__ x,    // [B,T,DIN]
    const float* __restrict__ Wx,   // [DIN,U]
    const float* __restrict__ Wh,   // [U,U]
    const float* __restrict__ bias, // [U]
    const float* __restrict__ Wd,   // [U,DOUT]
    const float* __restrict__ bd,   // [DOUT]
    float* __restrict__ out)        // [B,T,DOUT]
{
    // Wave 0 (consumer): pure recurrence. Wave 1 (producer): x-projection for
    // chunk c+1 and Dense epilogue for chunk c-1.
    __shared__ float xps[2][CHUNK * UU];       // scaled x-projection (+K) per chunk
    __shared__ float hist[2][CHUNK * HISTP];   // u history per chunk
    __shared__ __align__(16) float xs[CHUNK * 12];
    __shared__ __align__(8)  f32x2 wdl2[UU];   // -2*Wd rows

    const int tid = threadIdx.x;
    const int wid = tid >> 6;    // 0 = scan wave, 1 = producer wave
    const int l   = tid & 63;
    const int b   = blockIdx.x;
    const int g   = l >> 4;
    const int r   = l & 15;

    // --- probe DPP row_ror direction (init-only, direction-proof) ---
    int dstep;
    {
        int q = __builtin_amdgcn_mov_dpp(r, 0x121, 0xF, 0xF, false);
        dstep = (q - r) & 15;
    }

    // --- exact-value probe of the permlane swapadd network ---
    int mode = 2;
#if HAS_PL
    {
        float a = (float)l, bb = 100.0f + (float)l;
        float t32 = swapadd32(a, bb);
        float e32 = (l & 32) ? (2.0f * l + 168.0f) : (2.0f * l + 32.0f);
        float t16 = swapadd16(a, bb);
        float e16 = (l & 16) ? (2.0f * l + 184.0f) : (2.0f * l + 16.0f);
        if (__all(t32 == e32) && __all(t16 == e16)) mode = 0;
    }
#endif

    // --- Wh fragments, scaled: W2'[k,c] = -2*C*Wh[k,c]; columns cj = r + 16j ---
    f32x2 w2[4][8];
#pragma unroll
    for (int j = 0; j < 4; ++j) {
        const int cj = r + 16 * j;
#pragma unroll
        for (int m = 0; m < 8; ++m) {
            const int k0 = 16 * g + ((r + (2 * m) * dstep) & 15);
            const int k1 = 16 * g + ((r + (2 * m + 1) * dstep) & 15);
            f32x2 w;
            w.x = -2.0f * CSCALE * Wh[(size_t)k0 * UU + cj];
            w.y = -2.0f * CSCALE * Wh[(size_t)k1 * UU + cj];
            w2[j][m] = w;
        }
    }

    // --- producer-wave constants ---
    f32x2 wxp[5];
#pragma unroll
    for (int d2 = 0; d2 < 5; ++d2) {
        f32x2 w;
        w.x = CSCALE * Wx[(2 * d2) * UU + l];
        w.y = CSCALE * Wx[(2 * d2 + 1) * UU + l];
        wxp[d2] = w;
    }
    float Kl;
    {
        float s = bias[l];
        for (int k = 0; k < UU; ++k) s += Wh[(size_t)k * UU + l];
        Kl = CSCALE * s;
    }
    f32x2 bdd;
    {
        float s0 = bd[0], s1 = bd[1];
        for (int k = 0; k < UU; ++k) { s0 += Wd[k * DOUT + 0]; s1 += Wd[k * DOUT + 1]; }
        bdd.x = s0; bdd.y = s1;
    }
    if (wid == 0) {
        f32x2 w; w.x = -2.0f * Wd[l * DOUT + 0]; w.y = -2.0f * Wd[l * DOUT + 1];
        wdl2[l] = w;
    }

    const float* xb = x + (size_t)b * TT * DIN;
    float*       ob = out + (size_t)b * TT * DOUT;

    // --- producer helpers ---
    auto fill_xps = [&](int cn) {
        const f32x2* xr = (const f32x2*)(xb + (size_t)(cn * CHUNK + l) * DIN);
        f32x2 v0 = xr[0], v1 = xr[1], v2 = xr[2], v3 = xr[3], v4 = xr[4];
        f32x2* dst = (f32x2*)&xs[l * 12];
        dst[0] = v0; dst[1] = v1; dst[2] = v2; dst[3] = v3; dst[4] = v4;
        float* xp_out = &xps[cn & 1][l];
#pragma unroll 4
        for (int s = 0; s < CHUNK; ++s) {
            const float* p = &xs[s * 12];
            f32x4 xa = ((const f32x4*)p)[0];
            f32x4 xc = ((const f32x4*)p)[1];
            f32x2 xe = ((const f32x2*)p)[4];
            f32x2 acc = {Kl, 0.0f};
            acc = pkfma(__builtin_shufflevector(xa, xa, 0, 1), wxp[0], acc);
            acc = pkfma(__builtin_shufflevector(xa, xa, 2, 3), wxp[1], acc);
            acc = pkfma(__builtin_shufflevector(xc, xc, 0, 1), wxp[2], acc);
            acc = pkfma(__builtin_shufflevector(xc, xc, 2, 3), wxp[3], acc);
            acc = pkfma(xe, wxp[4], acc);
            xp_out[s * UU] = acc.x + acc.y;
        }
    };
    auto dense_chunk = [&](int cd) {
        const float* hrow = &hist[cd & 1][l * HISTP];
        f32x2 acc = bdd;
#pragma unroll 8
        for (int k = 0; k < UU; ++k) {
            float u = hrow[k];
            f32x2 uu; uu.x = u; uu.y = u;
            acc = pkfma(uu, wdl2[k], acc);
        }
        float2 o; o.x = acc.x; o.y = acc.y;
        *(float2*)(ob + (size_t)(cd * CHUNK + l) * DOUT) = o;
    };

    // prologue: producer fills chunk 0's x-projection
    if (wid == 1) fill_xps(0);
    __syncthreads();

    auto scan_chunk = [&](auto MC, int c, float u) {
        constexpr int MODE = decltype(MC)::value;
        const float* xpsrc = &xps[c & 1][l];
        float* hdst = &hist[c & 1][l];
#pragma unroll 8
        for (int s = 0; s < CHUNK; ++s) {
            float xpv = xpsrc[s * UU];          // independent of u -> hoistable
            // broadcast u within each 16-lane row, direct to pk pairs
            f32x2 hp[8];
            hp[0].x = u;
            ror_fill<1>(__float_as_int(u), hp);
            // dot with -2C*Wh: 8 accumulators, chain depth 4
            f32x2 a0a = {0.f,0.f}, a1a = {0.f,0.f}, a2a = {0.f,0.f}, a3a = {0.f,0.f};
            f32x2 a0b = {0.f,0.f}, a1b = {0.f,0.f}, a2b = {0.f,0.f}, a3b = {0.f,0.f};
#pragma unroll
            for (int m = 0; m < 4; ++m) {
                a0a = pkfma(hp[m], w2[0][m], a0a);
                a1a = pkfma(hp[m], w2[1][m], a1a);
                a2a = pkfma(hp[m], w2[2][m], a2a);
                a3a = pkfma(hp[m], w2[3][m], a3a);
            }
#pragma unroll
            for (int m = 4; m < 8; ++m) {
                a0b = pkfma(hp[m], w2[0][m], a0b);
                a1b = pkfma(hp[m], w2[1][m], a1b);
                a2b = pkfma(hp[m], w2[2][m], a2b);
                a3b = pkfma(hp[m], w2[3][m], a3b);
            }
            f32x2 a0 = a0a + a0b, a1 = a1a + a1b, a2 = a2a + a2b, a3 = a3a + a3b;
            float zr = reduce4<MODE>(a0.x + a0.y, a1.x + a1.y,
                                     a2.x + a2.y, a3.x + a3.y, l);
            float zp = zr + xpv;                // = C*z
#if __has_builtin(__builtin_amdgcn_exp2f)
            float e = __builtin_amdgcn_exp2f(zp);
#else
            float e = exp2f(zp);
#endif
            u = __builtin_amdgcn_rcpf(e + 1.0f);  // u = 1/(e^{2z}+1); h = 1-2u
            hdst[s * HISTP] = u;
        }
        return u;
    };

    float u = 0.5f;  // h_0 = 0
    for (int c = 0; c < NCHUNK; ++c) {
        if (wid == 0) {
            if (mode == 0) u = scan_chunk(IC<0>{}, c, u);
            else           u = scan_chunk(IC<2>{}, c, u);
        } else {
            if (c + 1 < NCHUNK) fill_xps(c + 1);
            if (c > 0)          dense_chunk(c - 1);
        }
        __syncthreads();
    }
    if (wid == 1) dense_chunk(NCHUNK - 1);
}

extern "C" void kernel_launch(void* const* d_in, const int* in_sizes, int n_in,
                              void* d_out, int out_size, void* d_ws, size_t ws_size,
                              hipStream_t stream) {
    const float* x    = (const float*)d_in[0];
    const float* Wx   = (const float*)d_in[1];
    const float* Wh   = (const float*)d_in[2];
    const float* bias = (const float*)d_in[3];
    const float* Wd   = (const float*)d_in[4];
    const float* bd   = (const float*)d_in[5];
    float* out = (float*)d_out;

    rnn_scan_kernel<<<BB, 128, 0, stream>>>(x, Wx, Wh, bias, Wd, bd, out);
}